// Round 1
// baseline (184.378 us; speedup 1.0000x reference)
//
#include <hip/hip_runtime.h>
#include <hip/hip_bf16.h>
#include <hip/hip_fp16.h>

#define FEAT 2048
#define NCLS 751
#define NPAD 768
#define NPRB 64
#define NGAL 256
#define WSCALE 256.0f

typedef _Float16 f16x8 __attribute__((ext_vector_type(8)));
typedef float f32x4 __attribute__((ext_vector_type(4)));

__device__ __forceinline__ unsigned short f2h_u(float x) {
  union { _Float16 h; unsigned short u; } v;
  v.h = (_Float16)x;
  return v.u;
}

// ---------------------------------------------------------------------------
// Kernel 1: per-feature moments of probe/gallery -> BN scale s[f], shift t[f]
// mean[f] = E_pg[(p-g)^2] = M2p - 2 M1p M1g + M2g   (exact, cross-product)
// E[d^2]  = M4p - 4 M3p M1g + 6 M2p M2g - 4 M1p M3g + M4g
// ---------------------------------------------------------------------------
__global__ void stats_kernel(const float* __restrict__ P, const float* __restrict__ G,
                             const float* __restrict__ gamma, const float* __restrict__ beta,
                             float* __restrict__ st) {
  int fx = threadIdx.x & 31, ry = threadIdx.x >> 5;
  int f = blockIdx.x * 32 + fx;
  float a1 = 0, a2 = 0, a3 = 0, a4 = 0;
  for (int r = ry; r < NPRB; r += 8) {
    float x = P[r * FEAT + f], x2 = x * x;
    a1 += x; a2 += x2; a3 += x2 * x; a4 += x2 * x2;
  }
  float b1 = 0, b2 = 0, b3 = 0, b4 = 0;
  for (int r = ry; r < NGAL; r += 8) {
    float x = G[r * FEAT + f], x2 = x * x;
    b1 += x; b2 += x2; b3 += x2 * x; b4 += x2 * x2;
  }
  __shared__ float red[8][8][32];
  float vals[8] = {a1, a2, a3, a4, b1, b2, b3, b4};
#pragma unroll
  for (int m = 0; m < 8; ++m) red[m][ry][fx] = vals[m];
  __syncthreads();
  if (ry == 0) {
    float mm[8];
#pragma unroll
    for (int m = 0; m < 8; ++m) {
      float sum = 0.f;
#pragma unroll
      for (int r = 0; r < 8; ++r) sum += red[m][r][fx];
      mm[m] = sum;
    }
    float M1p = mm[0] * (1.f / NPRB), M2p = mm[1] * (1.f / NPRB);
    float M3p = mm[2] * (1.f / NPRB), M4p = mm[3] * (1.f / NPRB);
    float M1g = mm[4] * (1.f / NGAL), M2g = mm[5] * (1.f / NGAL);
    float M3g = mm[6] * (1.f / NGAL), M4g = mm[7] * (1.f / NGAL);
    float mean = M2p - 2.f * M1p * M1g + M2g;
    float Ed2 = M4p - 4.f * M3p * M1g + 6.f * M2p * M2g - 4.f * M1p * M3g + M4g;
    float var = Ed2 - mean * mean;
    float sv = gamma[f] / sqrtf(var + 1e-5f);
    st[f] = sv;
    st[FEAT + f] = beta[f] - mean * sv;  // t[f]
  }
}

// ---------------------------------------------------------------------------
// Kernel 2: W'[c,f] = W[c,f] * s[f] * WSCALE  -> f16, padded to 768 rows
// ---------------------------------------------------------------------------
__global__ void prepb_kernel(const float* __restrict__ W, const float* __restrict__ st,
                             unsigned short* __restrict__ Wp) {
  int idx = (blockIdx.x * 256 + threadIdx.x) * 4;  // [0, 768*2048)
  int c = idx >> 11, f = idx & (FEAT - 1);
  float4 w = make_float4(0.f, 0.f, 0.f, 0.f);
  if (c < NCLS) w = *(const float4*)(W + (size_t)c * FEAT + f);
  float4 sv = *(const float4*)(st + f);
  unsigned int u0 = (unsigned int)f2h_u(w.x * sv.x * WSCALE) |
                    ((unsigned int)f2h_u(w.y * sv.y * WSCALE) << 16);
  unsigned int u1 = (unsigned int)f2h_u(w.z * sv.z * WSCALE) |
                    ((unsigned int)f2h_u(w.w * sv.w * WSCALE) << 16);
  uint2 u; u.x = u0; u.y = u1;
  *(uint2*)(Wp + idx) = u;
}

// ---------------------------------------------------------------------------
// Kernel 3: b'[c] = b[c] + sum_f t[f] * W[c,f]
// ---------------------------------------------------------------------------
__global__ void prepbias_kernel(const float* __restrict__ W, const float* __restrict__ b,
                                const float* __restrict__ st, float* __restrict__ bp) {
  int c = blockIdx.x;
  const float* t = st + FEAT;
  float acc = 0.f;
  for (int f = threadIdx.x; f < FEAT; f += 256) acc += t[f] * W[(size_t)c * FEAT + f];
#pragma unroll
  for (int off = 32; off > 0; off >>= 1) acc += __shfl_down(acc, off, 64);
  __shared__ float r[4];
  int wave = threadIdx.x >> 6, lane = threadIdx.x & 63;
  if (lane == 0) r[wave] = acc;
  __syncthreads();
  if (threadIdx.x == 0) bp[c] = b[c] + r[0] + r[1] + r[2] + r[3];
}

// ---------------------------------------------------------------------------
// Kernel 4: fused GEMM. M=16384 (p*256+g), N=768 (classes, padded), K=2048.
// A[n,k] = (P[p,k]-G[g,k])^2 generated on the fly (p fixed per M-tile).
// B = W' (f16, [N,K] row-major) via global_load_lds width=16 (m97 pattern).
// ---------------------------------------------------------------------------
#define AS_STRIDE 56  // elems; 112B row stride: 16B-aligned frags, 2-way banks (free)

__global__ __launch_bounds__(256, 3)
void gemm_kernel(const float* __restrict__ P, const float* __restrict__ G,
                 const unsigned short* __restrict__ Wp, const float* __restrict__ bp,
                 float* __restrict__ out) {
  __shared__ float Prow[FEAT];                 // 8 KB
  __shared__ unsigned short As[128 * AS_STRIDE];  // 14 KB
  __shared__ unsigned short Bs[128 * 32];      // 8 KB

  const int tid = threadIdx.x;
  const int lane = tid & 63, wave = tid >> 6;
  const int mtile = blockIdx.x, ntile = blockIdx.y;
  const int p = mtile >> 1;             // probe row (2 M-tiles per probe)
  const int g0 = (mtile & 1) * 128;     // gallery base row

  // preload the probe row into LDS (fp32, read-only thereafter)
  const float4* psrc = (const float4*)(P + (size_t)p * FEAT);
  ((float4*)Prow)[tid] = psrc[tid];
  ((float4*)Prow)[tid + 256] = psrc[tid + 256];

  f32x4 acc[4][4];
#pragma unroll
  for (int mi = 0; mi < 4; ++mi)
#pragma unroll
    for (int ni = 0; ni < 4; ++ni) acc[mi][ni] = (f32x4){0.f, 0.f, 0.f, 0.f};

  const int wm = (wave & 1) * 64, wn = (wave >> 1) * 64;

  // A-gen lane roles: 128 rows x 8 chunks of 4 floats; 4 passes of 256 threads
  const int arow = tid >> 3, ac4 = tid & 7;
  const float* gbase = G + (size_t)(g0 + arow) * FEAT + ac4 * 4;
  unsigned short* awr = As + arow * AS_STRIDE + ac4 * 4;

  // B-stage lane roles: 64 rows x 4 chunks of 8 f16 per instruction
  const int brow = tid >> 2, bchk = tid & 3;
  const unsigned short* bgbase = Wp + (size_t)(ntile * 128 + brow) * FEAT + bchk * 8;
  char* blds0 = (char*)Bs + wave * 1024;  // wave-uniform LDS base; HW adds lane*16

  for (int k0 = 0; k0 < FEAT; k0 += 32) {
    __syncthreads();
    // --- stage B: 128x32 f16 tile, 2 x global_load_lds_dwordx4 ---
    __builtin_amdgcn_global_load_lds(
        (const __attribute__((address_space(1))) void*)(bgbase + k0),
        (__attribute__((address_space(3))) void*)(blds0), 16, 0, 0);
    __builtin_amdgcn_global_load_lds(
        (const __attribute__((address_space(1))) void*)(bgbase + 64 * FEAT + k0),
        (__attribute__((address_space(3))) void*)(blds0 + 4096), 16, 0, 0);
    // --- stage A: compute (p-g)^2 -> f16, 128x32 tile ---
    float4 p4 = *(const float4*)(Prow + k0 + ac4 * 4);
#pragma unroll
    for (int j = 0; j < 4; ++j) {
      float4 g4 = *(const float4*)(gbase + (size_t)j * 32 * FEAT + k0);
      float dx = p4.x - g4.x, dy = p4.y - g4.y;
      float dz = p4.z - g4.z, dw = p4.w - g4.w;
      uint2 u;
      u.x = (unsigned int)f2h_u(dx * dx) | ((unsigned int)f2h_u(dy * dy) << 16);
      u.y = (unsigned int)f2h_u(dz * dz) | ((unsigned int)f2h_u(dw * dw) << 16);
      *(uint2*)(awr + j * 32 * AS_STRIDE) = u;
    }
    __syncthreads();
    // --- fragments + 16 MFMAs ---
    f16x8 af[4], bf[4];
#pragma unroll
    for (int mi = 0; mi < 4; ++mi)
      af[mi] = *(const f16x8*)(As + (wm + mi * 16 + (lane & 15)) * AS_STRIDE + (lane >> 4) * 8);
#pragma unroll
    for (int ni = 0; ni < 4; ++ni)
      bf[ni] = *(const f16x8*)(Bs + (wn + ni * 16 + (lane & 15)) * 32 + (lane >> 4) * 8);
#pragma unroll
    for (int mi = 0; mi < 4; ++mi)
#pragma unroll
      for (int ni = 0; ni < 4; ++ni)
        acc[mi][ni] = __builtin_amdgcn_mfma_f32_16x16x32_f16(af[mi], bf[ni], acc[mi][ni], 0, 0, 0);
  }

  // epilogue: C/D layout col=lane&15, row=(lane>>4)*4+reg; undo WSCALE, add b'
  const int col0 = ntile * 128 + wn + (lane & 15);
  const int row0 = mtile * 128 + wm + ((lane >> 4) << 2);
#pragma unroll
  for (int ni = 0; ni < 4; ++ni) {
    int col = col0 + ni * 16;
    if (col >= NCLS) continue;
    float bv = bp[col];
#pragma unroll
    for (int mi = 0; mi < 4; ++mi) {
      int row = row0 + mi * 16;
#pragma unroll
      for (int r = 0; r < 4; ++r)
        out[(size_t)(row + r) * NCLS + col] = acc[mi][ni][r] * (1.0f / WSCALE) + bv;
    }
  }
}

// ---------------------------------------------------------------------------
extern "C" void kernel_launch(void* const* d_in, const int* in_sizes, int n_in,
                              void* d_out, int out_size, void* d_ws, size_t ws_size,
                              hipStream_t stream) {
  const float* P = (const float*)d_in[0];      // [64, 2048]
  const float* G = (const float*)d_in[1];      // [256, 2048]
  const float* gamma = (const float*)d_in[2];  // [2048]
  const float* beta = (const float*)d_in[3];   // [2048]
  const float* W = (const float*)d_in[4];      // [751, 2048]
  const float* b = (const float*)d_in[5];      // [751]
  float* out = (float*)d_out;                  // [64, 256, 751]

  float* st = (float*)d_ws;                    // s[2048] then t[2048]
  float* bp = st + 2 * FEAT;                   // b'[768]
  unsigned short* Wp = (unsigned short*)(bp + NPAD);  // f16 W' [768, 2048]

  hipLaunchKernelGGL(stats_kernel, dim3(64), dim3(256), 0, stream, P, G, gamma, beta, st);
  hipLaunchKernelGGL(prepb_kernel, dim3(NPAD * FEAT / 1024), dim3(256), 0, stream, W, st, Wp);
  hipLaunchKernelGGL(prepbias_kernel, dim3(NCLS), dim3(256), 0, stream, W, b, st, bp);
  hipLaunchKernelGGL(gemm_kernel, dim3(128, 6), dim3(256), 0, stream, P, G, Wp, bp, out);
}

// Round 2
// 179.581 us; speedup vs baseline: 1.0267x; 1.0267x over previous
//
#include <hip/hip_runtime.h>
#include <hip/hip_bf16.h>
#include <hip/hip_fp16.h>

#define FEAT 2048
#define NCLS 751
#define NPAD 768
#define NPRB 64
#define NGAL 256
#define WSCALE 256.0f

typedef _Float16 f16x8 __attribute__((ext_vector_type(8)));
typedef float f32x4 __attribute__((ext_vector_type(4)));

__device__ __forceinline__ unsigned short f2h_u(float x) {
  union { _Float16 h; unsigned short u; } v;
  v.h = (_Float16)x;
  return v.u;
}

// ---------------------------------------------------------------------------
// Kernel 1: per-feature moments of probe/gallery -> BN scale s[f], shift t[f]
// mean[f] = E_pg[(p-g)^2] = M2p - 2 M1p M1g + M2g   (exact, cross-product)
// E[d^2]  = M4p - 4 M3p M1g + 6 M2p M2g - 4 M1p M3g + M4g
// ---------------------------------------------------------------------------
__global__ void stats_kernel(const float* __restrict__ P, const float* __restrict__ G,
                             const float* __restrict__ gamma, const float* __restrict__ beta,
                             float* __restrict__ st) {
  int fx = threadIdx.x & 31, ry = threadIdx.x >> 5;
  int f = blockIdx.x * 32 + fx;
  float a1 = 0, a2 = 0, a3 = 0, a4 = 0;
  for (int r = ry; r < NPRB; r += 8) {
    float x = P[r * FEAT + f], x2 = x * x;
    a1 += x; a2 += x2; a3 += x2 * x; a4 += x2 * x2;
  }
  float b1 = 0, b2 = 0, b3 = 0, b4 = 0;
  for (int r = ry; r < NGAL; r += 8) {
    float x = G[r * FEAT + f], x2 = x * x;
    b1 += x; b2 += x2; b3 += x2 * x; b4 += x2 * x2;
  }
  __shared__ float red[8][8][32];
  float vals[8] = {a1, a2, a3, a4, b1, b2, b3, b4};
#pragma unroll
  for (int m = 0; m < 8; ++m) red[m][ry][fx] = vals[m];
  __syncthreads();
  if (ry == 0) {
    float mm[8];
#pragma unroll
    for (int m = 0; m < 8; ++m) {
      float sum = 0.f;
#pragma unroll
      for (int r = 0; r < 8; ++r) sum += red[m][r][fx];
      mm[m] = sum;
    }
    float M1p = mm[0] * (1.f / NPRB), M2p = mm[1] * (1.f / NPRB);
    float M3p = mm[2] * (1.f / NPRB), M4p = mm[3] * (1.f / NPRB);
    float M1g = mm[4] * (1.f / NGAL), M2g = mm[5] * (1.f / NGAL);
    float M3g = mm[6] * (1.f / NGAL), M4g = mm[7] * (1.f / NGAL);
    float mean = M2p - 2.f * M1p * M1g + M2g;
    float Ed2 = M4p - 4.f * M3p * M1g + 6.f * M2p * M2g - 4.f * M1p * M3g + M4g;
    float var = Ed2 - mean * mean;
    float sv = gamma[f] / sqrtf(var + 1e-5f);
    st[f] = sv;
    st[FEAT + f] = beta[f] - mean * sv;  // t[f]
  }
}

// ---------------------------------------------------------------------------
// Kernel 2: W'[c,f] = W[c,f] * s[f] * WSCALE  -> f16, padded to 768 rows
// ---------------------------------------------------------------------------
__global__ void prepb_kernel(const float* __restrict__ W, const float* __restrict__ st,
                             unsigned short* __restrict__ Wp) {
  int idx = (blockIdx.x * 256 + threadIdx.x) * 4;  // [0, 768*2048)
  int c = idx >> 11, f = idx & (FEAT - 1);
  float4 w = make_float4(0.f, 0.f, 0.f, 0.f);
  if (c < NCLS) w = *(const float4*)(W + (size_t)c * FEAT + f);
  float4 sv = *(const float4*)(st + f);
  unsigned int u0 = (unsigned int)f2h_u(w.x * sv.x * WSCALE) |
                    ((unsigned int)f2h_u(w.y * sv.y * WSCALE) << 16);
  unsigned int u1 = (unsigned int)f2h_u(w.z * sv.z * WSCALE) |
                    ((unsigned int)f2h_u(w.w * sv.w * WSCALE) << 16);
  uint2 u; u.x = u0; u.y = u1;
  *(uint2*)(Wp + idx) = u;
}

// ---------------------------------------------------------------------------
// Kernel 3: b'[c] = b[c] + sum_f t[f] * W[c,f]
// ---------------------------------------------------------------------------
__global__ void prepbias_kernel(const float* __restrict__ W, const float* __restrict__ b,
                                const float* __restrict__ st, float* __restrict__ bp) {
  int c = blockIdx.x;
  const float* t = st + FEAT;
  float acc = 0.f;
  for (int f = threadIdx.x; f < FEAT; f += 256) acc += t[f] * W[(size_t)c * FEAT + f];
#pragma unroll
  for (int off = 32; off > 0; off >>= 1) acc += __shfl_down(acc, off, 64);
  __shared__ float r[4];
  int wave = threadIdx.x >> 6, lane = threadIdx.x & 63;
  if (lane == 0) r[wave] = acc;
  __syncthreads();
  if (threadIdx.x == 0) bp[c] = b[c] + r[0] + r[1] + r[2] + r[3];
}

// ---------------------------------------------------------------------------
// Kernel 4a: materialize A[n,f] = (P[p,f]-G[g,f])^2 as f16, n = p*256+g.
// One block per row; 256 threads x 8 elems. Write-BW bound (~67 MB).
// Same math as the verified on-the-fly path: f32 square, RNE cvt.
// ---------------------------------------------------------------------------
__global__ void agen_kernel(const float* __restrict__ P, const float* __restrict__ G,
                            unsigned short* __restrict__ A) {
  int n = blockIdx.x;
  int p = n >> 8, g = n & 255;
  int f = threadIdx.x * 8;
  const float4* p4 = (const float4*)(P + (size_t)p * FEAT + f);
  const float4* g4 = (const float4*)(G + (size_t)g * FEAT + f);
  float4 pa = p4[0], pb = p4[1];
  float4 ga = g4[0], gb = g4[1];
  float d0 = pa.x - ga.x, d1 = pa.y - ga.y, d2 = pa.z - ga.z, d3 = pa.w - ga.w;
  float d4 = pb.x - gb.x, d5 = pb.y - gb.y, d6 = pb.z - gb.z, d7 = pb.w - gb.w;
  uint4 u;
  u.x = (unsigned int)f2h_u(d0 * d0) | ((unsigned int)f2h_u(d1 * d1) << 16);
  u.y = (unsigned int)f2h_u(d2 * d2) | ((unsigned int)f2h_u(d3 * d3) << 16);
  u.z = (unsigned int)f2h_u(d4 * d4) | ((unsigned int)f2h_u(d5 * d5) << 16);
  u.w = (unsigned int)f2h_u(d6 * d6) | ((unsigned int)f2h_u(d7 * d7) << 16);
  *(uint4*)(A + (size_t)n * FEAT + f) = u;
}

// ---------------------------------------------------------------------------
// Kernel 4b: pure f16 GEMM, m97 structure. M=16384, N=768, K=2048.
// A (f16, materialized) and B = W' both staged via global_load_lds width=16.
// 128x128 block tile, 4 waves of 4x4 16x16x32 MFMAs, BK=32.
// ---------------------------------------------------------------------------
__global__ __launch_bounds__(256, 3)
void gemm_mat_kernel(const unsigned short* __restrict__ A,
                     const unsigned short* __restrict__ Wp,
                     const float* __restrict__ bp, float* __restrict__ out) {
  __shared__ unsigned short As[128 * 32];  // 8 KB
  __shared__ unsigned short Bs[128 * 32];  // 8 KB

  const int tid = threadIdx.x;
  const int lane = tid & 63, wave = tid >> 6;
  const int mtile = blockIdx.x, ntile = blockIdx.y;

  // staging roles: 64 rows x 4 chunks of 8 f16 per global_load_lds round
  const int srow = tid >> 2, schk = tid & 3;
  const unsigned short* ag = A + (size_t)(mtile * 128 + srow) * FEAT + schk * 8;
  const unsigned short* bg = Wp + (size_t)(ntile * 128 + srow) * FEAT + schk * 8;
  char* alds = (char*)As + wave * 1024;  // wave-uniform base; HW adds lane*16
  char* blds = (char*)Bs + wave * 1024;

  f32x4 acc[4][4];
#pragma unroll
  for (int mi = 0; mi < 4; ++mi)
#pragma unroll
    for (int ni = 0; ni < 4; ++ni) acc[mi][ni] = (f32x4){0.f, 0.f, 0.f, 0.f};

  const int wm = (wave & 1) * 64, wn = (wave >> 1) * 64;

  for (int k0 = 0; k0 < FEAT; k0 += 32) {
    __syncthreads();
    __builtin_amdgcn_global_load_lds(
        (const __attribute__((address_space(1))) void*)(ag + k0),
        (__attribute__((address_space(3))) void*)(alds), 16, 0, 0);
    __builtin_amdgcn_global_load_lds(
        (const __attribute__((address_space(1))) void*)(ag + (size_t)64 * FEAT + k0),
        (__attribute__((address_space(3))) void*)(alds + 4096), 16, 0, 0);
    __builtin_amdgcn_global_load_lds(
        (const __attribute__((address_space(1))) void*)(bg + k0),
        (__attribute__((address_space(3))) void*)(blds), 16, 0, 0);
    __builtin_amdgcn_global_load_lds(
        (const __attribute__((address_space(1))) void*)(bg + (size_t)64 * FEAT + k0),
        (__attribute__((address_space(3))) void*)(blds + 4096), 16, 0, 0);
    __syncthreads();  // compiler drains vmcnt(0) here: LDS tiles valid

    f16x8 af[4], bf[4];
#pragma unroll
    for (int mi = 0; mi < 4; ++mi)
      af[mi] = *(const f16x8*)(As + (wm + mi * 16 + (lane & 15)) * 32 + (lane >> 4) * 8);
#pragma unroll
    for (int ni = 0; ni < 4; ++ni)
      bf[ni] = *(const f16x8*)(Bs + (wn + ni * 16 + (lane & 15)) * 32 + (lane >> 4) * 8);
#pragma unroll
    for (int mi = 0; mi < 4; ++mi)
#pragma unroll
      for (int ni = 0; ni < 4; ++ni)
        acc[mi][ni] = __builtin_amdgcn_mfma_f32_16x16x32_f16(af[mi], bf[ni], acc[mi][ni], 0, 0, 0);
  }

  // epilogue: C/D layout col=lane&15, row=(lane>>4)*4+reg; undo WSCALE, add b'
  const int col0 = ntile * 128 + wn + (lane & 15);
  const int row0 = mtile * 128 + wm + ((lane >> 4) << 2);
#pragma unroll
  for (int ni = 0; ni < 4; ++ni) {
    int col = col0 + ni * 16;
    if (col >= NCLS) continue;
    float bv = bp[col];
#pragma unroll
    for (int mi = 0; mi < 4; ++mi) {
      int row = row0 + mi * 16;
#pragma unroll
      for (int r = 0; r < 4; ++r)
        out[(size_t)(row + r) * NCLS + col] = acc[mi][ni][r] * (1.0f / WSCALE) + bv;
    }
  }
}

// ---------------------------------------------------------------------------
// Fallback (ws too small): on-the-fly A-gen GEMM (round-1 verified kernel).
// ---------------------------------------------------------------------------
#define AS_STRIDE 56

__global__ __launch_bounds__(256, 3)
void gemm_fly_kernel(const float* __restrict__ P, const float* __restrict__ G,
                     const unsigned short* __restrict__ Wp, const float* __restrict__ bp,
                     float* __restrict__ out) {
  __shared__ float Prow[FEAT];
  __shared__ unsigned short As[128 * AS_STRIDE];
  __shared__ unsigned short Bs[128 * 32];

  const int tid = threadIdx.x;
  const int lane = tid & 63, wave = tid >> 6;
  const int mtile = blockIdx.x, ntile = blockIdx.y;
  const int p = mtile >> 1;
  const int g0 = (mtile & 1) * 128;

  const float4* psrc = (const float4*)(P + (size_t)p * FEAT);
  ((float4*)Prow)[tid] = psrc[tid];
  ((float4*)Prow)[tid + 256] = psrc[tid + 256];

  f32x4 acc[4][4];
#pragma unroll
  for (int mi = 0; mi < 4; ++mi)
#pragma unroll
    for (int ni = 0; ni < 4; ++ni) acc[mi][ni] = (f32x4){0.f, 0.f, 0.f, 0.f};

  const int wm = (wave & 1) * 64, wn = (wave >> 1) * 64;
  const int arow = tid >> 3, ac4 = tid & 7;
  const float* gbase = G + (size_t)(g0 + arow) * FEAT + ac4 * 4;
  unsigned short* awr = As + arow * AS_STRIDE + ac4 * 4;
  const int brow = tid >> 2, bchk = tid & 3;
  const unsigned short* bgbase = Wp + (size_t)(ntile * 128 + brow) * FEAT + bchk * 8;
  char* blds0 = (char*)Bs + wave * 1024;

  for (int k0 = 0; k0 < FEAT; k0 += 32) {
    __syncthreads();
    __builtin_amdgcn_global_load_lds(
        (const __attribute__((address_space(1))) void*)(bgbase + k0),
        (__attribute__((address_space(3))) void*)(blds0), 16, 0, 0);
    __builtin_amdgcn_global_load_lds(
        (const __attribute__((address_space(1))) void*)(bgbase + 64 * FEAT + k0),
        (__attribute__((address_space(3))) void*)(blds0 + 4096), 16, 0, 0);
    float4 p4 = *(const float4*)(Prow + k0 + ac4 * 4);
#pragma unroll
    for (int j = 0; j < 4; ++j) {
      float4 g4 = *(const float4*)(gbase + (size_t)j * 32 * FEAT + k0);
      float dx = p4.x - g4.x, dy = p4.y - g4.y;
      float dz = p4.z - g4.z, dw = p4.w - g4.w;
      uint2 u;
      u.x = (unsigned int)f2h_u(dx * dx) | ((unsigned int)f2h_u(dy * dy) << 16);
      u.y = (unsigned int)f2h_u(dz * dz) | ((unsigned int)f2h_u(dw * dw) << 16);
      *(uint2*)(awr + j * 32 * AS_STRIDE) = u;
    }
    __syncthreads();
    f16x8 af[4], bf[4];
#pragma unroll
    for (int mi = 0; mi < 4; ++mi)
      af[mi] = *(const f16x8*)(As + (wm + mi * 16 + (lane & 15)) * AS_STRIDE + (lane >> 4) * 8);
#pragma unroll
    for (int ni = 0; ni < 4; ++ni)
      bf[ni] = *(const f16x8*)(Bs + (wn + ni * 16 + (lane & 15)) * 32 + (lane >> 4) * 8);
#pragma unroll
    for (int mi = 0; mi < 4; ++mi)
#pragma unroll
      for (int ni = 0; ni < 4; ++ni)
        acc[mi][ni] = __builtin_amdgcn_mfma_f32_16x16x32_f16(af[mi], bf[ni], acc[mi][ni], 0, 0, 0);
  }

  const int col0 = ntile * 128 + wn + (lane & 15);
  const int row0 = mtile * 128 + wm + ((lane >> 4) << 2);
#pragma unroll
  for (int ni = 0; ni < 4; ++ni) {
    int col = col0 + ni * 16;
    if (col >= NCLS) continue;
    float bv = bp[col];
#pragma unroll
    for (int mi = 0; mi < 4; ++mi) {
      int row = row0 + mi * 16;
#pragma unroll
      for (int r = 0; r < 4; ++r)
        out[(size_t)(row + r) * NCLS + col] = acc[mi][ni][r] * (1.0f / WSCALE) + bv;
    }
  }
}

// ---------------------------------------------------------------------------
extern "C" void kernel_launch(void* const* d_in, const int* in_sizes, int n_in,
                              void* d_out, int out_size, void* d_ws, size_t ws_size,
                              hipStream_t stream) {
  const float* P = (const float*)d_in[0];
  const float* G = (const float*)d_in[1];
  const float* gamma = (const float*)d_in[2];
  const float* beta = (const float*)d_in[3];
  const float* W = (const float*)d_in[4];
  const float* b = (const float*)d_in[5];
  float* out = (float*)d_out;

  float* st = (float*)d_ws;                           // s[2048], t[2048]
  float* bp = st + 2 * FEAT;                          // b'[768]
  unsigned short* Wp = (unsigned short*)(bp + NPAD);  // f16 W' [768, 2048]
  unsigned short* A = Wp + (size_t)NPAD * FEAT;       // f16 A [16384, 2048]

  size_t need = (size_t)(2 * FEAT + NPAD) * 4 + (size_t)NPAD * FEAT * 2 +
                (size_t)NPRB * NGAL * FEAT * 2;

  hipLaunchKernelGGL(stats_kernel, dim3(64), dim3(256), 0, stream, P, G, gamma, beta, st);
  hipLaunchKernelGGL(prepb_kernel, dim3(NPAD * FEAT / 1024), dim3(256), 0, stream, W, st, Wp);
  hipLaunchKernelGGL(prepbias_kernel, dim3(NCLS), dim3(256), 0, stream, W, b, st, bp);

  if (ws_size >= need) {
    hipLaunchKernelGGL(agen_kernel, dim3(NPRB * NGAL), dim3(256), 0, stream, P, G, A);
    hipLaunchKernelGGL(gemm_mat_kernel, dim3(128, 6), dim3(256), 0, stream, A, Wp, bp, out);
  } else {
    hipLaunchKernelGGL(gemm_fly_kernel, dim3(128, 6), dim3(256), 0, stream, P, G, Wp, bp, out);
  }
}

// Round 3
// 166.808 us; speedup vs baseline: 1.1053x; 1.0766x over previous
//
#include <hip/hip_runtime.h>
#include <hip/hip_bf16.h>
#include <hip/hip_fp16.h>

#define FEAT 2048
#define NCLS 751
#define NPAD 768
#define NPRB 64
#define NGAL 256
#define WSCALE 256.0f

typedef _Float16 f16x8 __attribute__((ext_vector_type(8)));
typedef float f32x4 __attribute__((ext_vector_type(4)));

__device__ __forceinline__ unsigned short f2h_u(float x) {
  union { _Float16 h; unsigned short u; } v;
  v.h = (_Float16)x;
  return v.u;
}

// ---------------------------------------------------------------------------
// Kernel 1: per-feature moments of probe/gallery -> BN scale s[f], shift t[f]
// mean[f] = E_pg[(p-g)^2] = M2p - 2 M1p M1g + M2g   (exact, cross-product)
// E[d^2]  = M4p - 4 M3p M1g + 6 M2p M2g - 4 M1p M3g + M4g
// ---------------------------------------------------------------------------
__global__ void stats_kernel(const float* __restrict__ P, const float* __restrict__ G,
                             const float* __restrict__ gamma, const float* __restrict__ beta,
                             float* __restrict__ st) {
  int fx = threadIdx.x & 31, ry = threadIdx.x >> 5;
  int f = blockIdx.x * 32 + fx;
  float a1 = 0, a2 = 0, a3 = 0, a4 = 0;
  for (int r = ry; r < NPRB; r += 8) {
    float x = P[r * FEAT + f], x2 = x * x;
    a1 += x; a2 += x2; a3 += x2 * x; a4 += x2 * x2;
  }
  float b1 = 0, b2 = 0, b3 = 0, b4 = 0;
  for (int r = ry; r < NGAL; r += 8) {
    float x = G[r * FEAT + f], x2 = x * x;
    b1 += x; b2 += x2; b3 += x2 * x; b4 += x2 * x2;
  }
  __shared__ float red[8][8][32];
  float vals[8] = {a1, a2, a3, a4, b1, b2, b3, b4};
#pragma unroll
  for (int m = 0; m < 8; ++m) red[m][ry][fx] = vals[m];
  __syncthreads();
  if (ry == 0) {
    float mm[8];
#pragma unroll
    for (int m = 0; m < 8; ++m) {
      float sum = 0.f;
#pragma unroll
      for (int r = 0; r < 8; ++r) sum += red[m][r][fx];
      mm[m] = sum;
    }
    float M1p = mm[0] * (1.f / NPRB), M2p = mm[1] * (1.f / NPRB);
    float M3p = mm[2] * (1.f / NPRB), M4p = mm[3] * (1.f / NPRB);
    float M1g = mm[4] * (1.f / NGAL), M2g = mm[5] * (1.f / NGAL);
    float M3g = mm[6] * (1.f / NGAL), M4g = mm[7] * (1.f / NGAL);
    float mean = M2p - 2.f * M1p * M1g + M2g;
    float Ed2 = M4p - 4.f * M3p * M1g + 6.f * M2p * M2g - 4.f * M1p * M3g + M4g;
    float var = Ed2 - mean * mean;
    float sv = gamma[f] / sqrtf(var + 1e-5f);
    st[f] = sv;
    st[FEAT + f] = beta[f] - mean * sv;  // t[f]
  }
}

// ---------------------------------------------------------------------------
// Kernel 2 (fused): per class c:
//   Wp[c,f] = W[c,f] * s[f] * WSCALE (f16), bp[c] = b[c] + sum_f t[f] W[c,f]
// One block per padded class row; W read exactly once.
// ---------------------------------------------------------------------------
__global__ void prepw_kernel(const float* __restrict__ W, const float* __restrict__ b,
                             const float* __restrict__ st,
                             unsigned short* __restrict__ Wp, float* __restrict__ bp) {
  int c = blockIdx.x;
  int f = threadIdx.x * 8;
  float4 w0 = make_float4(0.f, 0.f, 0.f, 0.f), w1 = w0;
  if (c < NCLS) {
    const float4* wsrc = (const float4*)(W + (size_t)c * FEAT + f);
    w0 = wsrc[0]; w1 = wsrc[1];
  }
  const float4* s4 = (const float4*)(st + f);
  float4 s0 = s4[0], s1 = s4[1];
  const float4* t4 = (const float4*)(st + FEAT + f);
  float4 t0 = t4[0], t1 = t4[1];
  uint4 u;
  u.x = (unsigned int)f2h_u(w0.x * s0.x * WSCALE) | ((unsigned int)f2h_u(w0.y * s0.y * WSCALE) << 16);
  u.y = (unsigned int)f2h_u(w0.z * s0.z * WSCALE) | ((unsigned int)f2h_u(w0.w * s0.w * WSCALE) << 16);
  u.z = (unsigned int)f2h_u(w1.x * s1.x * WSCALE) | ((unsigned int)f2h_u(w1.y * s1.y * WSCALE) << 16);
  u.w = (unsigned int)f2h_u(w1.z * s1.z * WSCALE) | ((unsigned int)f2h_u(w1.w * s1.w * WSCALE) << 16);
  *(uint4*)(Wp + (size_t)c * FEAT + f) = u;
  float acc = t0.x * w0.x + t0.y * w0.y + t0.z * w0.z + t0.w * w0.w +
              t1.x * w1.x + t1.y * w1.y + t1.z * w1.z + t1.w * w1.w;
#pragma unroll
  for (int off = 32; off > 0; off >>= 1) acc += __shfl_down(acc, off, 64);
  __shared__ float r[4];
  int wave = threadIdx.x >> 6, lane = threadIdx.x & 63;
  if (lane == 0) r[wave] = acc;
  __syncthreads();
  if (threadIdx.x == 0) bp[c] = (c < NCLS ? b[c] : 0.f) + r[0] + r[1] + r[2] + r[3];
}

// ---------------------------------------------------------------------------
// Kernel 3: materialize A[n,f] = (P[p,f]-G[g,f])^2 as f16, n = p*256+g.
// ---------------------------------------------------------------------------
__global__ void agen_kernel(const float* __restrict__ P, const float* __restrict__ G,
                            unsigned short* __restrict__ A) {
  int n = blockIdx.x;
  int p = n >> 8, g = n & 255;
  int f = threadIdx.x * 8;
  const float4* p4 = (const float4*)(P + (size_t)p * FEAT + f);
  const float4* g4 = (const float4*)(G + (size_t)g * FEAT + f);
  float4 pa = p4[0], pb = p4[1];
  float4 ga = g4[0], gb = g4[1];
  float d0 = pa.x - ga.x, d1 = pa.y - ga.y, d2 = pa.z - ga.z, d3 = pa.w - ga.w;
  float d4 = pb.x - gb.x, d5 = pb.y - gb.y, d6 = pb.z - gb.z, d7 = pb.w - gb.w;
  uint4 u;
  u.x = (unsigned int)f2h_u(d0 * d0) | ((unsigned int)f2h_u(d1 * d1) << 16);
  u.y = (unsigned int)f2h_u(d2 * d2) | ((unsigned int)f2h_u(d3 * d3) << 16);
  u.z = (unsigned int)f2h_u(d4 * d4) | ((unsigned int)f2h_u(d5 * d5) << 16);
  u.w = (unsigned int)f2h_u(d6 * d6) | ((unsigned int)f2h_u(d7 * d7) << 16);
  *(uint4*)(A + (size_t)n * FEAT + f) = u;
}

// ---------------------------------------------------------------------------
// Kernel 4: f16 GEMM, M=16384, N=768, K=2048. BK=64, XOR-swizzled LDS.
// LDS layout: row-major [128][8 chunks of 8 f16]; slot s of row r holds
// global k-chunk s^(r&7) (swizzle applied to the *global* source address,
// since global_load_lds writes dest = wave_base + lane*16 rigidly).
// Fragment reads then hit all 32 banks across 8 lanes -> conflict-free.
// ---------------------------------------------------------------------------
__global__ __launch_bounds__(256, 3)
void gemm_mat_kernel(const unsigned short* __restrict__ A,
                     const unsigned short* __restrict__ Wp,
                     const float* __restrict__ bp, float* __restrict__ out) {
  __shared__ unsigned short As[128 * 64];  // 16 KB
  __shared__ unsigned short Bs[128 * 64];  // 16 KB

  const int tid = threadIdx.x;
  const int lane = tid & 63, wave = tid >> 6;
  const int mtile = blockIdx.x, ntile = blockIdx.y;

  // staging: inst j covers rows 32j..32j+31; thread t -> row 32j+(t>>3),
  // global k-chunk (t&7)^((t>>3)&7), landing in LDS slot t&7 of its row.
  const int srow = tid >> 3;                     // 0..31
  const int sch = (tid & 7) ^ (srow & 7);        // swizzled source chunk
  const unsigned short* ag = A + (size_t)(mtile * 128 + srow) * FEAT + sch * 8;
  const unsigned short* bg = Wp + (size_t)(ntile * 128 + srow) * FEAT + sch * 8;
  char* alds = (char*)As + wave * 1024;  // wave-uniform; HW adds lane*16
  char* blds = (char*)Bs + wave * 1024;

  f32x4 acc[4][4];
#pragma unroll
  for (int mi = 0; mi < 4; ++mi)
#pragma unroll
    for (int ni = 0; ni < 4; ++ni) acc[mi][ni] = (f32x4){0.f, 0.f, 0.f, 0.f};

  const int wm = (wave & 1) * 64, wn = (wave >> 1) * 64;
  const int frow = lane & 15, fsw = lane & 7, fk = lane >> 4;  // fragment roles

  for (int k0 = 0; k0 < FEAT; k0 += 64) {
    __syncthreads();
#pragma unroll
    for (int j = 0; j < 4; ++j) {
      __builtin_amdgcn_global_load_lds(
          (const __attribute__((address_space(1))) void*)(ag + k0 + (size_t)j * 32 * FEAT),
          (__attribute__((address_space(3))) void*)(alds + j * 4096), 16, 0, 0);
      __builtin_amdgcn_global_load_lds(
          (const __attribute__((address_space(1))) void*)(bg + k0 + (size_t)j * 32 * FEAT),
          (__attribute__((address_space(3))) void*)(blds + j * 4096), 16, 0, 0);
    }
    __syncthreads();  // vmcnt(0) drained here: tiles valid

#pragma unroll
    for (int kk = 0; kk < 2; ++kk) {
      const int slot = (kk * 4 + fk) ^ fsw;  // LDS slot holding k-chunk kk*4+fk
      f16x8 af[4], bf[4];
#pragma unroll
      for (int mi = 0; mi < 4; ++mi)
        af[mi] = *(const f16x8*)(As + (wm + mi * 16 + frow) * 64 + slot * 8);
#pragma unroll
      for (int ni = 0; ni < 4; ++ni)
        bf[ni] = *(const f16x8*)(Bs + (wn + ni * 16 + frow) * 64 + slot * 8);
#pragma unroll
      for (int mi = 0; mi < 4; ++mi)
#pragma unroll
        for (int ni = 0; ni < 4; ++ni)
          acc[mi][ni] = __builtin_amdgcn_mfma_f32_16x16x32_f16(af[mi], bf[ni], acc[mi][ni], 0, 0, 0);
    }
  }

  // epilogue: C/D layout col=lane&15, row=(lane>>4)*4+reg; undo WSCALE, add b'
  const int col0 = ntile * 128 + wn + (lane & 15);
  const int row0 = mtile * 128 + wm + ((lane >> 4) << 2);
#pragma unroll
  for (int ni = 0; ni < 4; ++ni) {
    int col = col0 + ni * 16;
    if (col >= NCLS) continue;
    float bv = bp[col];
#pragma unroll
    for (int mi = 0; mi < 4; ++mi) {
      int row = row0 + mi * 16;
#pragma unroll
      for (int r = 0; r < 4; ++r)
        out[(size_t)(row + r) * NCLS + col] = acc[mi][ni][r] * (1.0f / WSCALE) + bv;
    }
  }
}

// ---------------------------------------------------------------------------
extern "C" void kernel_launch(void* const* d_in, const int* in_sizes, int n_in,
                              void* d_out, int out_size, void* d_ws, size_t ws_size,
                              hipStream_t stream) {
  const float* P = (const float*)d_in[0];
  const float* G = (const float*)d_in[1];
  const float* gamma = (const float*)d_in[2];
  const float* beta = (const float*)d_in[3];
  const float* W = (const float*)d_in[4];
  const float* b = (const float*)d_in[5];
  float* out = (float*)d_out;

  float* st = (float*)d_ws;                           // s[2048], t[2048]
  float* bp = st + 2 * FEAT;                          // b'[768]
  unsigned short* Wp = (unsigned short*)(bp + NPAD);  // f16 W' [768, 2048]
  unsigned short* A = Wp + (size_t)NPAD * FEAT;       // f16 A [16384, 2048]

  hipLaunchKernelGGL(agen_kernel, dim3(NPRB * NGAL), dim3(256), 0, stream, P, G, A);
  hipLaunchKernelGGL(stats_kernel, dim3(64), dim3(256), 0, stream, P, G, gamma, beta, st);
  hipLaunchKernelGGL(prepw_kernel, dim3(NPAD), dim3(256), 0, stream, W, b, st, Wp, bp);
  hipLaunchKernelGGL(gemm_mat_kernel, dim3(128, 6), dim3(256), 0, stream, A, Wp, bp, out);
}